// Round 1
// baseline (438.341 us; speedup 1.0000x reference)
//
#include <hip/hip_runtime.h>

// PMF rating prediction: out[p] = relu(dot(U[user_ids[p]], V[item_ids[p]])), D=64.
// Memory-bound gather problem: 16 lanes/pair, float4 (16B) per lane covers the
// 256B row; shuffle-butterfly reduction within the 16-lane group.

constexpr int HIDDEN = 64;

__global__ __launch_bounds__(256) void pmf_dot_kernel(
    const float* __restrict__ user_emb,
    const float* __restrict__ item_emb,
    const int*   __restrict__ user_ids,
    const int*   __restrict__ item_ids,
    float*       __restrict__ out,
    int n_pairs)
{
    const int tid   = blockIdx.x * blockDim.x + threadIdx.x;
    const int pair  = tid >> 4;          // 16 lanes per pair
    const int lane16 = threadIdx.x & 15;
    if (pair >= n_pairs) return;

    const int uid = user_ids[pair];
    const int iid = item_ids[pair];

    const float4* __restrict__ up =
        reinterpret_cast<const float4*>(user_emb + (size_t)uid * HIDDEN) + lane16;
    const float4* __restrict__ vp =
        reinterpret_cast<const float4*>(item_emb + (size_t)iid * HIDDEN) + lane16;

    const float4 a = *up;
    const float4 b = *vp;

    float d = a.x * b.x + a.y * b.y + a.z * b.z + a.w * b.w;

    // Reduce across the 16 lanes of this pair's group (butterfly).
    d += __shfl_xor(d, 1, 16);
    d += __shfl_xor(d, 2, 16);
    d += __shfl_xor(d, 4, 16);
    d += __shfl_xor(d, 8, 16);

    if (lane16 == 0) {
        out[pair] = d > 0.0f ? d : 0.0f;
    }
}

extern "C" void kernel_launch(void* const* d_in, const int* in_sizes, int n_in,
                              void* d_out, int out_size, void* d_ws, size_t ws_size,
                              hipStream_t stream) {
    const float* user_emb = (const float*)d_in[0];
    const float* item_emb = (const float*)d_in[1];
    const int*   user_ids = (const int*)d_in[2];
    const int*   item_ids = (const int*)d_in[3];
    float* out = (float*)d_out;

    const int n_pairs = in_sizes[2];           // 2,000,000
    const int threads = 256;                   // 16 pairs per block
    const int pairs_per_block = threads / 16;
    const int blocks = (n_pairs + pairs_per_block - 1) / pairs_per_block;

    pmf_dot_kernel<<<blocks, threads, 0, stream>>>(
        user_emb, item_emb, user_ids, item_ids, out, n_pairs);
}

// Round 2
// 419.361 us; speedup vs baseline: 1.0453x; 1.0453x over previous
//
#include <hip/hip_runtime.h>

// PMF rating prediction: out[p] = relu(dot(U[user_ids[p]], V[item_ids[p]])), D=64.
// Latency-bound random gather: 16 lanes/pair-group, K=4 pairs per group so each
// thread has 8 independent float4 gathers in flight (MLP x4 vs round 1).

constexpr int HIDDEN = 64;
constexpr int K = 4;  // pairs per 16-lane group

__global__ __launch_bounds__(256) void pmf_dot_kernel(
    const float* __restrict__ user_emb,
    const float* __restrict__ item_emb,
    const int*   __restrict__ user_ids,
    const int*   __restrict__ item_ids,
    float*       __restrict__ out,
    int n_pairs)
{
    const int group  = (blockIdx.x * blockDim.x + threadIdx.x) >> 4;
    const int lane16 = threadIdx.x & 15;
    const int p0     = group * K;

    if (p0 + K <= n_pairs) {
        // Fast path: vector id loads, 8 gathers in flight, vector output store.
        const int4 u4 = *reinterpret_cast<const int4*>(user_ids + p0);
        const int4 i4 = *reinterpret_cast<const int4*>(item_ids + p0);

        const float4* up0 = reinterpret_cast<const float4*>(user_emb + (size_t)u4.x * HIDDEN) + lane16;
        const float4* up1 = reinterpret_cast<const float4*>(user_emb + (size_t)u4.y * HIDDEN) + lane16;
        const float4* up2 = reinterpret_cast<const float4*>(user_emb + (size_t)u4.z * HIDDEN) + lane16;
        const float4* up3 = reinterpret_cast<const float4*>(user_emb + (size_t)u4.w * HIDDEN) + lane16;
        const float4* vp0 = reinterpret_cast<const float4*>(item_emb + (size_t)i4.x * HIDDEN) + lane16;
        const float4* vp1 = reinterpret_cast<const float4*>(item_emb + (size_t)i4.y * HIDDEN) + lane16;
        const float4* vp2 = reinterpret_cast<const float4*>(item_emb + (size_t)i4.z * HIDDEN) + lane16;
        const float4* vp3 = reinterpret_cast<const float4*>(item_emb + (size_t)i4.w * HIDDEN) + lane16;

        // Issue all 8 loads before any use so they overlap.
        const float4 a0 = *up0, a1 = *up1, a2 = *up2, a3 = *up3;
        const float4 b0 = *vp0, b1 = *vp1, b2 = *vp2, b3 = *vp3;

        float d0 = a0.x * b0.x + a0.y * b0.y + a0.z * b0.z + a0.w * b0.w;
        float d1 = a1.x * b1.x + a1.y * b1.y + a1.z * b1.z + a1.w * b1.w;
        float d2 = a2.x * b2.x + a2.y * b2.y + a2.z * b2.z + a2.w * b2.w;
        float d3 = a3.x * b3.x + a3.y * b3.y + a3.z * b3.z + a3.w * b3.w;

        // Four independent 16-lane butterflies (interleaved for ILP).
        #pragma unroll
        for (int s = 1; s < 16; s <<= 1) {
            d0 += __shfl_xor(d0, s, 16);
            d1 += __shfl_xor(d1, s, 16);
            d2 += __shfl_xor(d2, s, 16);
            d3 += __shfl_xor(d3, s, 16);
        }

        if (lane16 == 0) {
            float4 r;
            r.x = d0 > 0.0f ? d0 : 0.0f;
            r.y = d1 > 0.0f ? d1 : 0.0f;
            r.z = d2 > 0.0f ? d2 : 0.0f;
            r.w = d3 > 0.0f ? d3 : 0.0f;
            *reinterpret_cast<float4*>(out + p0) = r;  // p0 % 4 == 0 -> 16B aligned
        }
    } else if (p0 < n_pairs) {
        // Tail: scalar per-pair fallback.
        for (int p = p0; p < n_pairs; ++p) {
            const int uid = user_ids[p];
            const int iid = item_ids[p];
            const float4 a = *(reinterpret_cast<const float4*>(user_emb + (size_t)uid * HIDDEN) + lane16);
            const float4 b = *(reinterpret_cast<const float4*>(item_emb + (size_t)iid * HIDDEN) + lane16);
            float d = a.x * b.x + a.y * b.y + a.z * b.z + a.w * b.w;
            #pragma unroll
            for (int s = 1; s < 16; s <<= 1) d += __shfl_xor(d, s, 16);
            if (lane16 == 0) out[p] = d > 0.0f ? d : 0.0f;
        }
    }
}

extern "C" void kernel_launch(void* const* d_in, const int* in_sizes, int n_in,
                              void* d_out, int out_size, void* d_ws, size_t ws_size,
                              hipStream_t stream) {
    const float* user_emb = (const float*)d_in[0];
    const float* item_emb = (const float*)d_in[1];
    const int*   user_ids = (const int*)d_in[2];
    const int*   item_ids = (const int*)d_in[3];
    float* out = (float*)d_out;

    const int n_pairs = in_sizes[2];                 // 2,000,000
    const int threads = 256;                         // 16 groups/block
    const int pairs_per_block = (threads / 16) * K;  // 64 pairs/block
    const int blocks = (n_pairs + pairs_per_block - 1) / pairs_per_block;

    pmf_dot_kernel<<<blocks, threads, 0, stream>>>(
        user_emb, item_emb, user_ids, item_ids, out, n_pairs);
}